// Round 3
// baseline (113.322 us; speedup 1.0000x reference)
//
#include <hip/hip_runtime.h>

// Spherical harmonics (real/imag), LMAX=4, N=1e6.
// Layout (verified R3/R8 PASS): PLANAR — out[0:N*25]=yr (N,25), out[N*25:]=yi.
//
// R(this): nontemporal wide stores, take 2. R9 failed to COMPILE only:
// __builtin_nontemporal_store rejects HIP_vector_type float4. Fix: native
// clang ext_vector_type(4) float (same 16B layout). Theory unchanged from R9:
// timed region = 400MB poison-fill (~61.5us, fixed) + kernel (~49us). The
// kernel's effective 4.3 TB/s (vs fill's 6.5 on the same buffer) is
// depressed by LLC thrash — the fill leaves >256MB dirty poison lines; our
// write-allocating stores force victim writebacks sharing the HBM write
// port. `nt` stores bypass LLC allocation: no victim evictions on our
// critical path, no fresh dirty lines left behind.
// Drain structure otherwise identical to the verified R8 kernel.

constexpr int BLOCK = 256;
constexpr int NC = 25;              // components per point per plane
constexpr int ROWF = BLOCK * NC;    // 6400 floats = 25.6 KB LDS -> 6 blocks/CU

typedef float floatx4 __attribute__((ext_vector_type(4)));  // nt-store-compatible

__global__ __launch_bounds__(BLOCK) void sh_kernel(
    const float* __restrict__ rhat, float* __restrict__ out,
    int n, long long out_size, int vec_ok) {
    __shared__ __align__(16) float lds[ROWF];
    const int tid = threadIdx.x;
    const int p = blockIdx.x * BLOCK + tid;

    float re[NC], im[NC];
    #pragma unroll
    for (int j = 0; j < NC; ++j) { re[j] = 0.0f; im[j] = 0.0f; }

    if (p < n) {
        const float rx = rhat[3 * p + 0];
        const float ry = rhat[3 * p + 1];
        const float rz = rhat[3 * p + 2];

        // --- Legendre (reference's recurrence, fp32 constants) ---
        const float p00 = 0.28209479177387814f;
        const float p10 = 0.4886025119029199f * rz;
        const float p11 = -0.34549414947133544f;
        const float p20 = 1.9364916731037085f * (rz * p10 + (-0.5773502691896257f) * p00);
        const float p21 = 2.23606797749979f * rz * p11;
        const float p22 = -1.118033988749895f * p11;
        const float p30 = 1.9720265943665387f * (rz * p20 + (-0.5163977794943222f) * p10);
        const float p31 = 2.091650066335189f  * (rz * p21 + (-0.4472135954999579f) * p11);
        const float p32 = 2.6457513110645906f * rz * p22;
        const float p33 = -1.0801234497346435f * p22;
        const float p40 = 1.984313483298443f  * (rz * p30 + (-0.50709255283711f)   * p20);
        const float p41 = 2.0493901531919196f * (rz * p31 + (-0.4780914437337574f) * p21);
        const float p42 = 2.29128784747792f   * (rz * p32 + (-0.3779644730092272f) * p22);
        const float p43 = 3.0f * rz * p33;
        const float p44 = -1.0606601717798212f * p33;

        // --- (rx + i ry)^m ---
        const float c1r = rx, c1i = ry;
        const float c2r = c1r * rx - c1i * ry, c2i = c1r * ry + c1i * rx;
        const float c3r = c2r * rx - c2i * ry, c3i = c2r * ry + c2i * rx;
        const float c4r = c3r * rx - c3i * ry, c4i = c3r * ry + c3i * rx;

        const float y11r = c1r * p11, y11i = c1i * p11;
        const float y21r = c1r * p21, y21i = c1i * p21;
        const float y22r = c2r * p22, y22i = c2i * p22;
        const float y31r = c1r * p31, y31i = c1i * p31;
        const float y32r = c2r * p32, y32i = c2i * p32;
        const float y33r = c3r * p33, y33i = c3i * p33;
        const float y41r = c1r * p41, y41i = c1i * p41;
        const float y42r = c2r * p42, y42i = c2i * p42;
        const float y43r = c3r * p43, y43i = c3i * p43;
        const float y44r = c4r * p44, y44i = c4i * p44;

        // order: l=0..4, m=-l..l; m<0: ph=(-1)^|m|, (r*ph, -i*ph)
        re[0]  = p00;                       // (0,0)
        re[1]  = -y11r;  im[1]  = y11i;     // (1,-1)
        re[2]  = p10;                       // (1,0)
        re[3]  = y11r;   im[3]  = y11i;     // (1,1)
        re[4]  = y22r;   im[4]  = -y22i;    // (2,-2)
        re[5]  = -y21r;  im[5]  = y21i;     // (2,-1)
        re[6]  = p20;                       // (2,0)
        re[7]  = y21r;   im[7]  = y21i;     // (2,1)
        re[8]  = y22r;   im[8]  = y22i;     // (2,2)
        re[9]  = -y33r;  im[9]  = y33i;     // (3,-3)
        re[10] = y32r;   im[10] = -y32i;    // (3,-2)
        re[11] = -y31r;  im[11] = y31i;     // (3,-1)
        re[12] = p30;                       // (3,0)
        re[13] = y31r;   im[13] = y31i;     // (3,1)
        re[14] = y32r;   im[14] = y32i;     // (3,2)
        re[15] = y33r;   im[15] = y33i;     // (3,3)
        re[16] = y44r;   im[16] = -y44i;    // (4,-4)
        re[17] = -y43r;  im[17] = y43i;     // (4,-3)
        re[18] = y42r;   im[18] = -y42i;    // (4,-2)
        re[19] = -y41r;  im[19] = y41i;     // (4,-1)
        re[20] = p40;                       // (4,0)
        re[21] = y41r;   im[21] = y41i;     // (4,1)
        re[22] = y42r;   im[22] = y42i;     // (4,2)
        re[23] = y43r;   im[23] = y43i;     // (4,3)
        re[24] = y44r;   im[24] = y44i;     // (4,4)
    }

    const long long plane = (long long)n * NC;              // 25e6 elements
    const long long base  = (long long)blockIdx.x * ROWF;   // mult of 4
    const long long rem   = plane - base;
    const int valid = (int)(rem < (long long)ROWF ? rem : (long long)ROWF);
    const int nvec  = valid >> 2;   // full float4s this block-plane

    // Drain LDS[0..valid) to out[gbase..gbase+valid), nontemporal.
    // gbase is a multiple of 4 elements when vec_ok (checked host-side).
    auto drain = [&](const long long gbase) {
        if (vec_ok) {
            for (int v = tid; v < nvec; v += BLOCK) {
                const long long g = gbase + 4LL * v;        // 16B-aligned
                if (g + 3 < out_size) {
                    __builtin_nontemporal_store(
                        *reinterpret_cast<const floatx4*>(&lds[4 * v]),
                        reinterpret_cast<floatx4*>(&out[g]));
                }
            }
            for (int e = (nvec << 2) + tid; e < valid; e += BLOCK) {
                const long long g = gbase + e;              // generic tail
                if (g < out_size) __builtin_nontemporal_store(lds[e], &out[g]);
            }
        } else {
            for (int e = tid; e < valid; e += BLOCK) {      // scalar fallback
                const long long g = gbase + e;
                if (g < out_size) __builtin_nontemporal_store(lds[e], &out[g]);
            }
        }
    };

    // ---- plane 0: real ----
    #pragma unroll
    for (int j = 0; j < NC; ++j) lds[tid * NC + j] = re[j];  // stride 25: 2/bank, free
    __syncthreads();
    drain(base);
    __syncthreads();   // re-use LDS

    // ---- plane 1: imag ----
    #pragma unroll
    for (int j = 0; j < NC; ++j) lds[tid * NC + j] = im[j];
    __syncthreads();
    drain(plane + base);
}

extern "C" void kernel_launch(void* const* d_in, const int* in_sizes, int n_in,
                              void* d_out, int out_size, void* d_ws, size_t ws_size,
                              hipStream_t stream) {
    const float* rhat = (const float*)d_in[0];
    float* out = (float*)d_out;
    const int n = in_sizes[0] / 3;
    const long long plane = (long long)n * NC;
    // Vector path only when every dwordx4 store is provably 16B-aligned:
    // out base 16B-aligned AND plane offset a multiple of 4 elements.
    const int vec_ok =
        ((((uintptr_t)d_out) & 15) == 0) && ((plane & 3LL) == 0);
    const int grid = (n + BLOCK - 1) / BLOCK;
    sh_kernel<<<grid, BLOCK, 0, stream>>>(rhat, out, n, (long long)out_size, vec_ok);
}

// Round 4
// 110.421 us; speedup vs baseline: 1.0263x; 1.0263x over previous
//
#include <hip/hip_runtime.h>

// Spherical harmonics (real/imag), LMAX=4, N=1e6.
// Layout (verified R3/R8 PASS): PLANAR — out[0:N*25]=yr (N,25), out[N*25:]=yi.
//
// R(this): LDS-only barriers (no vmcnt drain). Evidence chain:
//  - R8 (float4 drain) PASS, null delta -> store width/VALU not the limit.
//  - R10 (nt stores) PASS, null delta; fill's WRITE_SIZE=400MB during its own
//    dispatch -> poison streams to HBM in the fill, no dirty-LLC writeback
//    tax on us -> LLC-thrash theory dead. nt reverted.
//  - Remaining structural difference vs the 6.5 TB/s fill: __syncthreads
//    emits s_waitcnt vmcnt(0) before s_barrier -> each wave issues ~7 stores
//    then stalls until ALL are acked (convoy, 3x per block). Mid-kernel
//    barriers only need to order LDS: drain's ds_reads must complete before
//    the next plane's ds_writes. Outstanding global stores never touch LDS.
//  - Fix: raw s_barrier preceded by lgkmcnt(0) ONLY (inline asm, "memory"
//    clobber + sched_barrier(0) fences per guide rule #18). Stores stay in
//    flight across all barriers -> fill-like deep store queue.
// Occupancy unchanged: 25.6 KB LDS -> 6 blocks/CU. Data flow byte-identical
// to the verified R8 kernel; only the sync instructions differ.

constexpr int BLOCK = 256;
constexpr int NC = 25;              // components per point per plane
constexpr int ROWF = BLOCK * NC;    // 6400 floats = 25.6 KB LDS -> 6 blocks/CU

// Workgroup barrier ordering LDS only: waves drain their own LDS ops
// (lgkmcnt) then sync. Global stores (vmcnt) intentionally NOT drained.
__device__ __forceinline__ void barrier_lds_only() {
    __builtin_amdgcn_sched_barrier(0);
    asm volatile("s_waitcnt lgkmcnt(0)" ::: "memory");
    __builtin_amdgcn_sched_barrier(0);
    __builtin_amdgcn_s_barrier();
    __builtin_amdgcn_sched_barrier(0);
}

__global__ __launch_bounds__(BLOCK) void sh_kernel(
    const float* __restrict__ rhat, float* __restrict__ out,
    int n, long long out_size, int vec_ok) {
    __shared__ __align__(16) float lds[ROWF];
    const int tid = threadIdx.x;
    const int p = blockIdx.x * BLOCK + tid;

    float re[NC], im[NC];
    #pragma unroll
    for (int j = 0; j < NC; ++j) { re[j] = 0.0f; im[j] = 0.0f; }

    if (p < n) {
        const float rx = rhat[3 * p + 0];
        const float ry = rhat[3 * p + 1];
        const float rz = rhat[3 * p + 2];

        // --- Legendre (reference's recurrence, fp32 constants) ---
        const float p00 = 0.28209479177387814f;
        const float p10 = 0.4886025119029199f * rz;
        const float p11 = -0.34549414947133544f;
        const float p20 = 1.9364916731037085f * (rz * p10 + (-0.5773502691896257f) * p00);
        const float p21 = 2.23606797749979f * rz * p11;
        const float p22 = -1.118033988749895f * p11;
        const float p30 = 1.9720265943665387f * (rz * p20 + (-0.5163977794943222f) * p10);
        const float p31 = 2.091650066335189f  * (rz * p21 + (-0.4472135954999579f) * p11);
        const float p32 = 2.6457513110645906f * rz * p22;
        const float p33 = -1.0801234497346435f * p22;
        const float p40 = 1.984313483298443f  * (rz * p30 + (-0.50709255283711f)   * p20);
        const float p41 = 2.0493901531919196f * (rz * p31 + (-0.4780914437337574f) * p21);
        const float p42 = 2.29128784747792f   * (rz * p32 + (-0.3779644730092272f) * p22);
        const float p43 = 3.0f * rz * p33;
        const float p44 = -1.0606601717798212f * p33;

        // --- (rx + i ry)^m ---
        const float c1r = rx, c1i = ry;
        const float c2r = c1r * rx - c1i * ry, c2i = c1r * ry + c1i * rx;
        const float c3r = c2r * rx - c2i * ry, c3i = c2r * ry + c2i * rx;
        const float c4r = c3r * rx - c3i * ry, c4i = c3r * ry + c3i * rx;

        const float y11r = c1r * p11, y11i = c1i * p11;
        const float y21r = c1r * p21, y21i = c1i * p21;
        const float y22r = c2r * p22, y22i = c2i * p22;
        const float y31r = c1r * p31, y31i = c1i * p31;
        const float y32r = c2r * p32, y32i = c2i * p32;
        const float y33r = c3r * p33, y33i = c3i * p33;
        const float y41r = c1r * p41, y41i = c1i * p41;
        const float y42r = c2r * p42, y42i = c2i * p42;
        const float y43r = c3r * p43, y43i = c3i * p43;
        const float y44r = c4r * p44, y44i = c4i * p44;

        // order: l=0..4, m=-l..l; m<0: ph=(-1)^|m|, (r*ph, -i*ph)
        re[0]  = p00;                       // (0,0)
        re[1]  = -y11r;  im[1]  = y11i;     // (1,-1)
        re[2]  = p10;                       // (1,0)
        re[3]  = y11r;   im[3]  = y11i;     // (1,1)
        re[4]  = y22r;   im[4]  = -y22i;    // (2,-2)
        re[5]  = -y21r;  im[5]  = y21i;     // (2,-1)
        re[6]  = p20;                       // (2,0)
        re[7]  = y21r;   im[7]  = y21i;     // (2,1)
        re[8]  = y22r;   im[8]  = y22i;     // (2,2)
        re[9]  = -y33r;  im[9]  = y33i;     // (3,-3)
        re[10] = y32r;   im[10] = -y32i;    // (3,-2)
        re[11] = -y31r;  im[11] = y31i;     // (3,-1)
        re[12] = p30;                       // (3,0)
        re[13] = y31r;   im[13] = y31i;     // (3,1)
        re[14] = y32r;   im[14] = y32i;     // (3,2)
        re[15] = y33r;   im[15] = y33i;     // (3,3)
        re[16] = y44r;   im[16] = -y44i;    // (4,-4)
        re[17] = -y43r;  im[17] = y43i;     // (4,-3)
        re[18] = y42r;   im[18] = -y42i;    // (4,-2)
        re[19] = -y41r;  im[19] = y41i;     // (4,-1)
        re[20] = p40;                       // (4,0)
        re[21] = y41r;   im[21] = y41i;     // (4,1)
        re[22] = y42r;   im[22] = y42i;     // (4,2)
        re[23] = y43r;   im[23] = y43i;     // (4,3)
        re[24] = y44r;   im[24] = y44i;     // (4,4)
    }

    const long long plane = (long long)n * NC;              // 25e6 elements
    const long long base  = (long long)blockIdx.x * ROWF;   // mult of 4
    const long long rem   = plane - base;
    const int valid = (int)(rem < (long long)ROWF ? rem : (long long)ROWF);
    const int nvec  = valid >> 2;   // full float4s this block-plane

    // Drain LDS[0..valid) to out[gbase..gbase+valid). Plain cached stores
    // (nt was null, R10). gbase mult-of-4 when vec_ok (checked host-side).
    auto drain = [&](const long long gbase) {
        if (vec_ok) {
            for (int v = tid; v < nvec; v += BLOCK) {
                const long long g = gbase + 4LL * v;        // 16B-aligned
                if (g + 3 < out_size) {
                    *reinterpret_cast<float4*>(&out[g]) =
                        *reinterpret_cast<const float4*>(&lds[4 * v]);
                }
            }
            for (int e = (nvec << 2) + tid; e < valid; e += BLOCK) {
                const long long g = gbase + e;              // generic tail
                if (g < out_size) out[g] = lds[e];
            }
        } else {
            for (int e = tid; e < valid; e += BLOCK) {      // scalar fallback
                const long long g = gbase + e;
                if (g < out_size) out[g] = lds[e];
            }
        }
    };

    // ---- plane 0: real ----
    #pragma unroll
    for (int j = 0; j < NC; ++j) lds[tid * NC + j] = re[j];  // stride 25: 2/bank, free
    barrier_lds_only();        // ds_writes visible; stores (none yet) untouched
    drain(base);               // stores issued, left in flight
    barrier_lds_only();        // all waves' ds_READS of lds done -> safe to reuse

    // ---- plane 1: imag ----
    #pragma unroll
    for (int j = 0; j < NC; ++j) lds[tid * NC + j] = im[j];
    barrier_lds_only();
    drain(plane + base);
    // no end-of-kernel drain needed: dispatch-boundary release handles stores
}

extern "C" void kernel_launch(void* const* d_in, const int* in_sizes, int n_in,
                              void* d_out, int out_size, void* d_ws, size_t ws_size,
                              hipStream_t stream) {
    const float* rhat = (const float*)d_in[0];
    float* out = (float*)d_out;
    const int n = in_sizes[0] / 3;
    const long long plane = (long long)n * NC;
    // Vector path only when every dwordx4 store is provably 16B-aligned:
    // out base 16B-aligned AND plane offset a multiple of 4 elements.
    const int vec_ok =
        ((((uintptr_t)d_out) & 15) == 0) && ((plane & 3LL) == 0);
    const int grid = (n + BLOCK - 1) / BLOCK;
    sh_kernel<<<grid, BLOCK, 0, stream>>>(rhat, out, n, (long long)out_size, vec_ok);
}